// Round 2
// baseline (68.486 us; speedup 1.0000x reference)
//
#include <hip/hip_runtime.h>

// Zoom: out[b,c,t,f] = w*x[..., floor(f*k/n)] + (1-w)*x[..., floor(f*k/n)+1]
// Shape [8,16,256,1024] fp32; k, n are runtime device scalars (k=2, n=3 here).
// R0: 67.8us, latency-bound on gathers (~300 cyc/wave-row = 1 L2 round-trip).
// R1: unroll 4 rows/iteration -> 32 loads in flight, amortize latency 4x.

constexpr int F = 1024;          // last-dim size from reference shape
constexpr int VEC = 4;           // outputs per thread
constexpr int BLOCK = F / VEC;   // 256 threads: one block covers one full row
constexpr int RU = 4;            // rows unrolled per iteration

__global__ __launch_bounds__(BLOCK) void zoom_kernel(
    const float* __restrict__ x,
    const int* __restrict__ kp,
    const int* __restrict__ np_,
    float* __restrict__ out,
    int nrows) {
  const int k = kp[0];
  const int n = np_[0];

  const int f0 = threadIdx.x * VEC;

  // Loop-invariant interpolation coefficients for this thread's 4 columns.
  int  idx0[VEC], idx1[VEC];
  float w0[VEC], w1[VEC];
#pragma unroll
  for (int j = 0; j < VEC; ++j) {
    const int f   = f0 + j;
    const int pos = f * k;          // integer numerator of f*k/n
    const int id  = pos / n;        // floor(f*k/n)
    const int rem = pos - id * n;
    const float w = 1.0f - (float)rem / (float)n;  // matches reference op order
    const bool v0 = id < F;
    const bool v1 = (id + 1) < F;
    w0[j]   = v0 ? w : 0.0f;
    w1[j]   = v1 ? (1.0f - w) : 0.0f;
    idx0[j] = v0 ? id : 0;                      // clamped; weight already zeroed
    idx1[j] = v1 ? (id + 1) : (F - 1);
  }

  const int nchunks = (nrows + RU - 1) / RU;

  for (int chunk = blockIdx.x; chunk < nchunks; chunk += gridDim.x) {
    const size_t row0 = (size_t)chunk * RU;

    if (row0 + RU <= (size_t)nrows) {
      // Fast path: issue all RU*2*VEC = 32 independent gathers first.
      float a[RU][VEC], b[RU][VEC];
#pragma unroll
      for (int r = 0; r < RU; ++r) {
        const float* __restrict__ xr = x + (row0 + r) * F;
#pragma unroll
        for (int j = 0; j < VEC; ++j) {
          a[r][j] = xr[idx0[j]];
          b[r][j] = xr[idx1[j]];
        }
      }
#pragma unroll
      for (int r = 0; r < RU; ++r) {
        float4 v;
        v.x = w0[0] * a[r][0] + w1[0] * b[r][0];
        v.y = w0[1] * a[r][1] + w1[1] * b[r][1];
        v.z = w0[2] * a[r][2] + w1[2] * b[r][2];
        v.w = w0[3] * a[r][3] + w1[3] * b[r][3];
        *reinterpret_cast<float4*>(out + (row0 + r) * F + f0) = v;
      }
    } else {
      // Tail: per-row.
      for (size_t row = row0; row < (size_t)nrows; ++row) {
        const float* __restrict__ xr = x + row * F;
        float4 v;
        v.x = w0[0] * xr[idx0[0]] + w1[0] * xr[idx1[0]];
        v.y = w0[1] * xr[idx0[1]] + w1[1] * xr[idx1[1]];
        v.z = w0[2] * xr[idx0[2]] + w1[2] * xr[idx1[2]];
        v.w = w0[3] * xr[idx0[3]] + w1[3] * xr[idx1[3]];
        *reinterpret_cast<float4*>(out + row * F + f0) = v;
      }
    }
  }
}

extern "C" void kernel_launch(void* const* d_in, const int* in_sizes, int n_in,
                              void* d_out, int out_size, void* d_ws, size_t ws_size,
                              hipStream_t stream) {
  const float* x   = (const float*)d_in[0];
  const int*   kp  = (const int*)d_in[1];
  const int*   np_ = (const int*)d_in[2];
  float* out = (float*)d_out;

  const int total = in_sizes[0];        // 8*16*256*1024
  const int nrows = total / F;          // 32768

  // 2048 blocks = 8 blocks/CU * 256 CUs; each block handles 4 chunks of 4 rows.
  const int nchunks = (nrows + RU - 1) / RU;
  const int grid = (nchunks < 2048) ? nchunks : 2048;
  zoom_kernel<<<grid, BLOCK, 0, stream>>>(x, kp, np_, out, nrows);
}

// Round 3
// 39.834 us; speedup vs baseline: 1.7193x; 1.7193x over previous
//
#include <hip/hip_runtime.h>

// Zoom: out[b,c,t,f] = w*x[..., floor(f*k/n)] + (1-w)*x[..., floor(f*k/n)+1]
// Shape [8,16,256,1024] fp32; k, n runtime device scalars (k=2, n=3 here).
// R0 (67.8us): scalar global gathers, latency theory.
// R1 (68.5us): 4x row unroll, NO change despite 2x less occupancy ->
//   bottleneck is gather address-coalescing throughput (TA/L1), not latency.
// R2: stage rows in LDS via coalesced float4 loads (only the ~2/3 of the row
//   actually referenced), gather from LDS instead. Kills the TA bound.

constexpr int F = 1024;          // last-dim size from reference shape
constexpr int VEC = 4;           // outputs per thread
constexpr int BLOCK = F / VEC;   // 256 threads: one block covers one full row
constexpr int RU = 4;            // rows staged per barrier pair (16 KB LDS)

__global__ __launch_bounds__(BLOCK) void zoom_kernel(
    const float* __restrict__ x,
    const int* __restrict__ kp,
    const int* __restrict__ np_,
    float* __restrict__ out,
    int nrows) {
  __shared__ float lds[RU][F];

  const int k = kp[0];
  const int n = np_[0];

  const int f0 = threadIdx.x * VEC;

  // Loop-invariant interpolation coefficients for this thread's 4 columns.
  int  idx0[VEC], idx1[VEC];
  float w0[VEC], w1[VEC];
#pragma unroll
  for (int j = 0; j < VEC; ++j) {
    const int f   = f0 + j;
    const int pos = f * k;          // integer numerator of f*k/n
    const int id  = pos / n;        // floor(f*k/n)
    const int rem = pos - id * n;
    const float w = 1.0f - (float)rem / (float)n;  // matches reference op order
    const bool v0 = id < F;
    const bool v1 = (id + 1) < F;
    w0[j]   = v0 ? w : 0.0f;
    w1[j]   = v1 ? (1.0f - w) : 0.0f;
    idx0[j] = v0 ? id : 0;                      // clamped; weight already zeroed
    idx1[j] = v1 ? (id + 1) : (F - 1);
  }

  // Highest source word referenced with nonzero weight: floor((F-1)*k/n)+1.
  int nwords = ((F - 1) * k) / n + 2;
  if (nwords > F) nwords = F;

  const int nchunks = (nrows + RU - 1) / RU;

  for (int chunk = blockIdx.x; chunk < nchunks; chunk += gridDim.x) {
    const size_t row0 = (size_t)chunk * RU;
    const int rcnt = ((size_t)nrows - row0 < (size_t)RU) ? (int)(nrows - row0) : RU;

    // Stage: coalesced float4 loads of the referenced prefix of each row.
    for (int r = 0; r < rcnt; ++r) {
      const float* __restrict__ xr = x + (row0 + r) * F;
      for (int w = f0; w < nwords; w += BLOCK * VEC) {
        // w is a multiple of 4 and < F, so w+3 <= F-1: always in-row.
        *reinterpret_cast<float4*>(&lds[r][w]) =
            *reinterpret_cast<const float4*>(xr + w);
      }
    }
    __syncthreads();

    // Gather from LDS + coalesced float4 store.
    for (int r = 0; r < rcnt; ++r) {
      float4 v;
      v.x = w0[0] * lds[r][idx0[0]] + w1[0] * lds[r][idx1[0]];
      v.y = w0[1] * lds[r][idx0[1]] + w1[1] * lds[r][idx1[1]];
      v.z = w0[2] * lds[r][idx0[2]] + w1[2] * lds[r][idx1[2]];
      v.w = w0[3] * lds[r][idx0[3]] + w1[3] * lds[r][idx1[3]];
      *reinterpret_cast<float4*>(out + (row0 + r) * F + f0) = v;
    }
    __syncthreads();   // protect LDS before next chunk's stores
  }
}

extern "C" void kernel_launch(void* const* d_in, const int* in_sizes, int n_in,
                              void* d_out, int out_size, void* d_ws, size_t ws_size,
                              hipStream_t stream) {
  const float* x   = (const float*)d_in[0];
  const int*   kp  = (const int*)d_in[1];
  const int*   np_ = (const int*)d_in[2];
  float* out = (float*)d_out;

  const int total = in_sizes[0];        // 8*16*256*1024
  const int nrows = total / F;          // 32768

  const int nchunks = (nrows + RU - 1) / RU;   // 8192
  const int grid = (nchunks < 2048) ? nchunks : 2048;
  zoom_kernel<<<grid, BLOCK, 0, stream>>>(x, kp, np_, out, nrows);
}